// Round 1
// baseline (41.051 us; speedup 1.0000x reference)
//
#include <hip/hip_runtime.h>

// Problem geometry (fixed by reference): B*T = 128 batches, N = 65536 rows, 3 coords.
constexpr int N_ROWS  = 65536;
constexpr int NBATCH  = 128;
constexpr int THREADS = 256;

// Key identity: out[b,c] = sqrt(min_d ( ra[b,c] - 2*mul[b,c,d] + rb[b,d] )).
// The argmin+gather+renorm in the reference is algebraically the same value,
// so a single pass over pred/target computing 15 sums per batch suffices.

__global__ __launch_bounds__(THREADS)
void nn_partial_kernel(const float* __restrict__ pred,
                       const float* __restrict__ targ,
                       float* __restrict__ partial,
                       int bpb, int npass) {
    const int bid   = blockIdx.x;
    const int batch = bid / bpb;
    const int chunk = bid - batch * bpb;
    const int rows_per_block = N_ROWS / bpb;
    const long base = (long)batch * (N_ROWS * 3) + (long)chunk * rows_per_block * 3;
    const float4* __restrict__ p4 = reinterpret_cast<const float4*>(pred + base);
    const float4* __restrict__ t4 = reinterpret_cast<const float4*>(targ + base);

    // acc[0..2]=ra[c], acc[3..5]=rb[d], acc[6..14]=mul[c][d]
    float acc[15];
    #pragma unroll
    for (int i = 0; i < 15; ++i) acc[i] = 0.f;

    const int tid = threadIdx.x;
    for (int pass = 0; pass < npass; ++pass) {
        // Each thread: 4 rows = 12 floats = 3 float4 from each input.
        // 48B-aligned since row index is a multiple of 4.
        const int v = (pass * THREADS + tid) * 3;
        float4 a0 = p4[v + 0], a1 = p4[v + 1], a2 = p4[v + 2];
        float4 b0 = t4[v + 0], b1 = t4[v + 1], b2 = t4[v + 2];
        float pr[4][3] = {{a0.x, a0.y, a0.z}, {a0.w, a1.x, a1.y},
                          {a1.z, a1.w, a2.x}, {a2.y, a2.z, a2.w}};
        float tr[4][3] = {{b0.x, b0.y, b0.z}, {b0.w, b1.x, b1.y},
                          {b1.z, b1.w, b2.x}, {b2.y, b2.z, b2.w}};
        #pragma unroll
        for (int r = 0; r < 4; ++r) {
            #pragma unroll
            for (int c = 0; c < 3; ++c) {
                acc[c]     = fmaf(pr[r][c], pr[r][c], acc[c]);
                acc[3 + c] = fmaf(tr[r][c], tr[r][c], acc[3 + c]);
            }
            #pragma unroll
            for (int c = 0; c < 3; ++c)
                #pragma unroll
                for (int d = 0; d < 3; ++d)
                    acc[6 + c * 3 + d] = fmaf(pr[r][c], tr[r][d], acc[6 + c * 3 + d]);
        }
    }

    // Wave (64-lane) butterfly reduce for each of the 15 accumulators.
    #pragma unroll
    for (int off = 32; off > 0; off >>= 1) {
        #pragma unroll
        for (int i = 0; i < 15; ++i)
            acc[i] += __shfl_down(acc[i], off, 64);
    }

    __shared__ float wsum[4][15];
    const int wave = tid >> 6;
    const int lane = tid & 63;
    if (lane == 0) {
        #pragma unroll
        for (int i = 0; i < 15; ++i) wsum[wave][i] = acc[i];
    }
    __syncthreads();
    if (tid < 15) {
        partial[(long)bid * 15 + tid] =
            wsum[0][tid] + wsum[1][tid] + wsum[2][tid] + wsum[3][tid];
    }
}

__global__ void nn_final_kernel(const float* __restrict__ partial,
                                float* __restrict__ out, int bpb) {
    const int b = threadIdx.x;
    if (b >= NBATCH) return;
    float s[15];
    #pragma unroll
    for (int i = 0; i < 15; ++i) s[i] = 0.f;
    for (int k = 0; k < bpb; ++k) {
        const float* pp = partial + (long)(b * bpb + k) * 15;
        #pragma unroll
        for (int i = 0; i < 15; ++i) s[i] += pp[i];
    }
    #pragma unroll
    for (int c = 0; c < 3; ++c) {
        float m = 3.0e38f;
        #pragma unroll
        for (int d = 0; d < 3; ++d) {
            float dist = s[c] - 2.0f * s[6 + c * 3 + d] + s[3 + d];
            m = fminf(m, dist);
        }
        out[b * 3 + c] = sqrtf(fmaxf(m, 0.f));
    }
}

extern "C" void kernel_launch(void* const* d_in, const int* in_sizes, int n_in,
                              void* d_out, int out_size, void* d_ws, size_t ws_size,
                              hipStream_t stream) {
    const float* pred = (const float*)d_in[0];
    const float* targ = (const float*)d_in[1];
    float* out      = (float*)d_out;
    float* partial  = (float*)d_ws;

    // Blocks per batch: prefer 16 (2048 blocks -> 8 blocks/CU), shrink if ws is tiny.
    int bpb = 16;
    while (bpb > 1 && (size_t)(NBATCH * bpb) * 15 * sizeof(float) > ws_size) bpb >>= 1;
    const int rows_per_block = N_ROWS / bpb;
    const int npass = rows_per_block / (THREADS * 4);

    nn_partial_kernel<<<NBATCH * bpb, THREADS, 0, stream>>>(pred, targ, partial, bpb, npass);
    nn_final_kernel<<<1, 128, 0, stream>>>(partial, out, bpb);
}